// Round 13
// baseline (169.157 us; speedup 1.0000x reference)
//
#include <hip/hip_runtime.h>
#include <hip/hip_bf16.h>

#define N_NODES 50000
#define N_EDGES 800000
#define HEADS   4
#define NEG_SLOPE 0.2f
#define CAP     64                    // bucket row: 63 edge slots + count in slot 63
#define NT      ((N_NODES + 63) / 64)       // 782 row blocks
#define EPB     4096                  // edges per edge-block (every 4th block)
#define NREG    391                   // regions of 128 nodes (dst>>7)
#define NREP    8                     // qcnt replicas (kills same-addr atomic chain)
#define QSUB    384                   // sub-queue cap: mean 256 + 8 sigma
#define NAGG    (N_NODES / 16)        // 3125 agg blocks (EXACT: 16*3125 = 50000)
#define INV_LN2 1.44269504088896340736f

typedef __attribute__((ext_vector_type(8))) _Float16 half8;  // 8 f16 (4 VGPRs)
typedef __attribute__((ext_vector_type(4))) float f32x4;     // MFMA acc
typedef __attribute__((ext_vector_type(8))) unsigned short u16x8; // 16B of f16 bits

template <typename T> __device__ __forceinline__ float cvt(T v);
template <> __device__ __forceinline__ float cvt<float>(float v) { return v; }
template <> __device__ __forceinline__ float cvt<__hip_bfloat16>(__hip_bfloat16 v) {
    return __bfloat162float(v);
}
__device__ __forceinline__ unsigned short f2h(float f) {     // f32 -> f16 bits (RNE)
    _Float16 h = (_Float16)f;
    return __builtin_bit_cast(unsigned short, h);
}
__device__ __forceinline__ float hbits(unsigned short u) {   // f16 bits -> f32
    return (float)__builtin_bit_cast(_Float16, u);           // folds into v_fma_mix
}
__device__ __forceinline__ int probe_fp32(const unsigned* xw) {
    int sane = 0;
    for (int j = 0; j < 64; ++j) {
        unsigned e = (xw[j] >> 7) & 0xFF;    // exponent of low half viewed as bf16
        sane += (e >= 90 && e <= 141);
    }
    return sane < 32;                        // junk low halves => fp32 buffer
}
__device__ __forceinline__ float loadW(int isf32, const void* W, int idx) {
    return isf32 ? ((const float*)W)[idx]
                 : cvt<__hip_bfloat16>(((const __hip_bfloat16*)W)[idx]);
}

// load 8 contiguous elems as f16, vectorized (b128 loads)
template <typename T>
__device__ __forceinline__ void load8_f16(const T* p, _Float16* dst);
template <>
__device__ __forceinline__ void load8_f16<float>(const float* p, _Float16* dst) {
    float4 a = *(const float4*)p;            // 32B-aligned (offsets are 8-float mult.)
    float4 b = *(const float4*)(p + 4);
    dst[0] = (_Float16)a.x; dst[1] = (_Float16)a.y;
    dst[2] = (_Float16)a.z; dst[3] = (_Float16)a.w;
    dst[4] = (_Float16)b.x; dst[5] = (_Float16)b.y;
    dst[6] = (_Float16)b.z; dst[7] = (_Float16)b.w;
}
template <>
__device__ __forceinline__ void load8_f16<__hip_bfloat16>(const __hip_bfloat16* p,
                                                          _Float16* dst) {
    uint4 a = *(const uint4*)p;              // 8 bf16 = 16B
    const unsigned short* u = (const unsigned short*)&a;
#pragma unroll
    for (int j = 0; j < 8; ++j)
        dst[j] = (_Float16)__uint_as_float(((unsigned)u[j]) << 16);
}

// ------------- fused init: probes + zero qcnt + pack Batt + Bpost -----------
// flags[0]: edge_index is int64. flags[1]: float inputs are fp32.
// Block 0: flags + zero qcnt (8 replicas). Block 1: att-fold Batt = (W @ a)/ln2
// in MFMA-B layout. Blocks 2..5: Bpost = Wstack[256,64]/4 in MFMA-B layout,
// Wstack[h*64+k, c] = W[k, h*64+c] (mean folded). B layout (HW-verified):
// within one K=32 MFMA, value(l,j)=B[k=(l>>4)*8+j][n=l&15].
__global__ __launch_bounds__(256) void k_init(const unsigned* __restrict__ xw,
                                              const int* __restrict__ ei,
                                              const void* __restrict__ W,
                                              const void* __restrict__ att_src,
                                              const void* __restrict__ att_dst,
                                              int* __restrict__ qcnt,
                                              int* __restrict__ flags,
                                              unsigned short* __restrict__ Batt,
                                              unsigned short* __restrict__ Bpost) {
    __shared__ float waS[256], waD[256];
    __shared__ int f32sh;
    if (blockIdx.x == 0) {
        for (int t = threadIdx.x; t < NREP * NREG; t += 256) qcnt[t] = 0;
        if (threadIdx.x == 0) {
            int all0 = 1;
            for (int j = 1; j < 64; j += 2) all0 &= (ei[j] == 0);
            flags[0] = all0;
            flags[1] = probe_fp32(xw);
        }
        return;
    }
    const int pb = blockIdx.x - 1;           // 0 = att fold, 1..4 = Bpost
    if (threadIdx.x == 0) f32sh = probe_fp32(xw);   // local probe (race-free)
    __syncthreads();
    const int isf32 = f32sh;
    if (pb == 0) {
        int t = threadIdx.x, k = t >> 2, h = t & 3;
        float s = 0.f, d = 0.f;
        for (int c = 0; c < 64; ++c) {
            float w = loadW(isf32, W, k * 256 + h * 64 + c);
            float as = isf32 ? ((const float*)att_src)[h * 64 + c]
                             : cvt<__hip_bfloat16>(((const __hip_bfloat16*)att_src)[h * 64 + c]);
            float ad = isf32 ? ((const float*)att_dst)[h * 64 + c]
                             : cvt<__hip_bfloat16>(((const __hip_bfloat16*)att_dst)[h * 64 + c]);
            s = fmaf(w, as, s);
            d = fmaf(w, ad, d);
        }
        waS[t] = s * INV_LN2;
        waD[t] = d * INV_LN2;
        __syncthreads();
        if (threadIdx.x < 128) {
            int r = threadIdx.x;             // r = q*64 + l, q = K-half
            int q = (r >> 6) & 1, l = r & 63, n = l & 15;
            int kbase = q * 32 + ((l >> 4) & 3) * 8;
#pragma unroll
            for (int j = 0; j < 8; ++j) {
                int kk = kbase + j;
                float v = (n < 4) ? waS[kk * 4 + n]
                        : (n < 8) ? waD[kk * 4 + (n - 4)] : 0.f;
                Batt[r * 8 + j] = f2h(v);
            }
        }
    } else {
        // Bpost: tile t = kt*4+nt (t = 0..31); this block packs 8 tiles.
        const int sub = threadIdx.x >> 5, s = threadIdx.x & 31;
        const int t = (pb - 1) * 8 + sub;
        const int kt = t >> 2, nt = t & 3;
#pragma unroll
        for (int e = 0; e < 16; ++e) {
            int idx = s * 16 + e;            // 0..511 within tile
            int l = idx >> 3, j = idx & 7;
            int rs = kt * 32 + ((l >> 4) & 3) * 8 + j;   // row of Wstack (0..255)
            int h = rs >> 6, k_in = rs & 63;
            int c = nt * 16 + (l & 15);
            Bpost[t * 512 + l * 8 + j] =
                f2h(loadW(isf32, W, k_in * 256 + h * 64 + c) * 0.25f);
        }
    }
}

// ---------------- logits + x->f16 from MFMA afrags (all k_mid blocks) --------
// Block = 64 rows, 4 waves; wave w: rows 16w..16w+15; single n-tile (Batt).
// C layout (HW-verified): col=lane&15, row=quad*4+reg. Cols 0..3 = a_src heads,
// 4..7 = a_dst heads (1/ln2-scaled) -> direct fp32 global writes.
// x16 is stored FROM the already-converted afrag registers.
template <typename T>
__device__ __forceinline__ void row_body(const T* __restrict__ x,
                                         const unsigned short* __restrict__ Batt,
                                         unsigned short* __restrict__ x16,
                                         float* __restrict__ a_src,
                                         float* __restrict__ a_dst) {
    const int tid = threadIdx.x;
    const int wav = tid >> 6, lane = tid & 63;
    const int quad = lane >> 4, r15 = lane & 15;
    const int m0 = blockIdx.x * 64;
    const int grow_a = m0 + wav * 16 + r15;     // this lane's A row (m = lane&15)
    int gr = grow_a;
    if (gr >= N_NODES) gr = N_NODES - 1;        // clamp; stores guarded
    half8 afrag[2];
#pragma unroll
    for (int q = 0; q < 2; ++q) {
        _Float16 tmp[8];
        load8_f16<T>(x + (size_t)gr * 64 + q * 32 + quad * 8, tmp);
#pragma unroll
        for (int j = 0; j < 8; ++j) afrag[q][j] = tmp[j];
    }
    // ---- f16 copy of x straight from registers (16B per store, full lines) -
    if (grow_a < N_NODES) {
#pragma unroll
        for (int q = 0; q < 2; ++q)
            *(half8*)(x16 + (size_t)grow_a * 64 + q * 32 + quad * 8) = afrag[q];
    }
    f32x4 acc = (f32x4){0.f, 0.f, 0.f, 0.f};
    const half8* bp = (const half8*)Batt;
    acc = __builtin_amdgcn_mfma_f32_16x16x32_f16(afrag[0], bp[lane], acc, 0, 0, 0);
    acc = __builtin_amdgcn_mfma_f32_16x16x32_f16(afrag[1], bp[64 + lane], acc, 0, 0, 0);
    if (r15 < 8) {
#pragma unroll
        for (int r = 0; r < 4; ++r) {
            int grow = m0 + wav * 16 + quad * 4 + r;
            if (grow < N_NODES) {
                if (r15 < 4) a_src[grow * HEADS + r15]       = acc[r];
                else         a_dst[grow * HEADS + (r15 - 4)] = acc[r];
            }
        }
    }
}

// ---------------- fused mid: rows + REGION-BUCKETED edge append -------------
// Every 4th block buckets EPB=4096 edges into 391 region queues (dst>>7) as
// packed 4B records — R12 post-mortem: doubling the chunk size (10.5 records
// ~42B vs 21B) halves the partial-line write-allocate on queue (9.7->4.9 MB)
// and halves total qcnt atomics. reg derived from rec (rec>>23) — no third
// array; lpos = -1 flags invalid. qcnt replicated 8x (rep = eb&7).
__global__ __launch_bounds__(256) void k_mid(const void* __restrict__ x,
                                             const unsigned short* __restrict__ Batt,
                                             const int* __restrict__ ei,
                                             const int* __restrict__ flags,
                                             int* __restrict__ qcnt,
                                             unsigned* __restrict__ queue,
                                             unsigned short* __restrict__ x16,
                                             float* __restrict__ a_src,
                                             float* __restrict__ a_dst) {
    __shared__ int hist[NREG];
    __shared__ int qbaseS[NREG];
    const int tid = threadIdx.x;
    const bool edge_blk = ((blockIdx.x & 3) == 0);   // 196 edge blocks, spread
    const int eb = blockIdx.x >> 2;                  // 0..195
    const int rep = eb & (NREP - 1);                 // my qcnt replica
    unsigned rec[16]; int lpos[16];
    int histv0 = 0, histv1 = 0, mybase0 = 0, mybase1 = 0;
    if (edge_blk) {
        for (int t = tid; t < NREG; t += 256) hist[t] = 0;
        __syncthreads();
        const int f64 = flags[0];
        const int pbase = eb * 2048 + tid;           // pair index (2 edges/pair)
#pragma unroll
        for (int k = 0; k < 8; ++k) {
            int pid = pbase + k * 256;
            int e = 2 * pid;
            if (e < N_EDGES) {                       // N_EDGES even => e+1 valid
                int s0, d0, s1, d1;
                if (f64) {                           // 16B = 2 int64 edges
                    int4 sv = *(const int4*)(ei + 2 * e);
                    int4 dv = *(const int4*)(ei + 2 * N_EDGES + 2 * e);
                    s0 = sv.x; s1 = sv.z; d0 = dv.x; d1 = dv.z;
                } else {                             // 8B = 2 int32 edges
                    int2 sv = *(const int2*)(ei + e);
                    int2 dv = *(const int2*)(ei + N_EDGES + e);
                    s0 = sv.x; s1 = sv.y; d0 = dv.x; d1 = dv.y;
                }
                rec[2 * k]     = (unsigned)s0 | ((unsigned)d0 << 16);
                rec[2 * k + 1] = (unsigned)s1 | ((unsigned)d1 << 16);
                lpos[2 * k] = 0; lpos[2 * k + 1] = 0;
            } else { lpos[2 * k] = -1; lpos[2 * k + 1] = -1; }
        }
#pragma unroll
        for (int k = 0; k < 16; ++k)
            if (lpos[k] >= 0) lpos[k] = atomicAdd(&hist[rec[k] >> 23], 1);
        __syncthreads();
        {   // qcnt atomics issued BEFORE row_body (round trip hides under it)
            int t0 = tid, t1 = tid + 256;
            histv0 = hist[t0];
            if (histv0) mybase0 = atomicAdd(qcnt + rep * NREG + t0, histv0);
            if (t1 < NREG) {
                histv1 = hist[t1];
                if (histv1) mybase1 = atomicAdd(qcnt + rep * NREG + t1, histv1);
            }
        }
    }
    // ---- rows for ALL blocks ----
    if (flags[1]) row_body<float>((const float*)x, Batt, x16, a_src, a_dst);
    else          row_body<__hip_bfloat16>((const __hip_bfloat16*)x, Batt,
                                           x16, a_src, a_dst);
    if (edge_blk) {
        qbaseS[tid] = mybase0;
        if (tid + 256 < NREG) qbaseS[tid + 256] = mybase1;
        __syncthreads();
#pragma unroll
        for (int k = 0; k < 16; ++k)
            if (lpos[k] >= 0) {
                int reg = rec[k] >> 23;              // dst>>7 (s is low 16b)
                int o = qbaseS[reg] + lpos[k];
                if (o < QSUB)
                    queue[((size_t)reg * NREP + rep) * QSUB + o] = rec[k];
            }
    }
}

// ---------------- scat: per-region 8 sub-queues -> col_pad (L2-local) -------
// One block per 128-node region (16 KB col_pad window, single-XCD L2).
// Positions via LDS atomics. Per-node count stored IN col_pad slot 63
// (self-loop occupies lane n <= 63, so slot 63 is never an edge slot).
__global__ __launch_bounds__(256) void k_scat(const unsigned* __restrict__ queue,
                                              const int* __restrict__ qcnt,
                                              unsigned short* __restrict__ col_pad) {
    __shared__ int cl[128];
    __shared__ int mr[NREP];
    const int b = blockIdx.x, tid = threadIdx.x;
    const int base = b << 7;
    if (tid < 128) cl[tid] = 0;
    if (tid < NREP) {
        int m = qcnt[tid * NREG + b];
        mr[tid] = m > QSUB ? QSUB : m;
    }
    __syncthreads();
#pragma unroll
    for (int rep = 0; rep < NREP; ++rep) {
        int m = mr[rep];
        const unsigned* q = queue + ((size_t)b * NREP + rep) * QSUB;
        for (int i = tid; i < m; i += 256) {
            unsigned rec = q[i];
            int d = rec >> 16, s = rec & 0xffff;
            int p = atomicAdd(&cl[d - base], 1);
            if (p < CAP - 1) col_pad[(size_t)d * CAP + p] = (unsigned short)s;
        }
    }
    __syncthreads();
    if (tid < 128) {
        int j = base + tid;
        if (j < N_NODES) {
            int c = cl[tid]; c = c > CAP - 1 ? CAP - 1 : c;
            col_pad[(size_t)j * CAP + (CAP - 1)] = (unsigned short)c;
        }
    }
}

// -------- fused aggregate+post (R10 structure + register-pe denominator) ----
// 16 nodes/block, 256 thr / 4 waves, 4 serial nodes/wave; 2 edges/round with
// parity-interleaved col/pe lists; unroll-8; count from col_pad slot 63.
// R12 trim: denominators come from a 6-level shfl_xor tree over the REGISTER
// pe (each lane holds its own edge's pe from the prologue) — removes the 4
// redundant VALU adds/edge from the hot loop (~30% of loop VALU); the tree
// runs on the DS pipe, parallel to VALU. Sum order changes only f32 jitter.
template <typename T>
__device__ __forceinline__ void agg_body(const unsigned short* __restrict__ col_pad,
                                         const float* __restrict__ a_src,
                                         const float* __restrict__ a_dst,
                                         const unsigned short* __restrict__ x16,
                                         const unsigned short* __restrict__ Bpost,
                                         const T* __restrict__ bias,
                                         const T* __restrict__ fc_w,
                                         const T* __restrict__ fc_b,
                                         float* __restrict__ out,
                                         int* __restrict__ cS,
                                         float4* __restrict__ peS,
                                         unsigned* __restrict__ sS,
                                         float* __restrict__ postS) {
    const int tid = threadIdx.x;
    const int wav = tid >> 6, lane = tid & 63;
    const int hlf = lane >> 5, l5 = lane & 31;
    const int quad = lane >> 4, r15 = lane & 15;
    const int nbase = blockIdx.x * 16 + wav * 4;            // 4 serial nodes/wave
    int* cSw = cS + wav * 64;
    float4* peSw = peS + wav * 64;
    const int slot = (lane & 1) * 32 + (lane >> 1);         // parity interleave
    const char* xb = (const char*)x16 + l5 * 4;             // my dim-pair slice
    int cval = (int)col_pad[(size_t)nbase * CAP + lane];    // node 0 row
#pragma unroll
    for (int nid = 0; nid < 4; ++nid) {
        const int wid = nbase + nid;
        int cval_next = 0;
        if (nid < 3)                                        // prefetch next row:
            cval_next = (int)col_pad[(size_t)(wid + 1) * CAP + lane];
        const int n = __shfl(cval, 63, 64);                 // count from slot 63
        const float4 ad = ((const float4*)a_dst)[wid];      // uniform
        const int mycol = (lane < n) ? cval : wid;          // lane n = self loop
        const float4 as = ((const float4*)a_src)[mycol];
        float e0 = as.x + ad.x, e1 = as.y + ad.y;
        float e2 = as.z + ad.z, e3 = as.w + ad.w;
        e0 = e0 > 0.f ? e0 : NEG_SLOPE * e0;  e1 = e1 > 0.f ? e1 : NEG_SLOPE * e1;
        e2 = e2 > 0.f ? e2 : NEG_SLOPE * e2;  e3 = e3 > 0.f ? e3 : NEG_SLOPE * e3;
        float4 pe = make_float4(exp2f(e0), exp2f(e1), exp2f(e2), exp2f(e3));
        if (lane > n) pe = make_float4(0.f, 0.f, 0.f, 0.f); // pad lanes
        cSw[slot] = mycol << 7;                             // x16 row BYTE offset
        peSw[slot] = pe;                                    // wave-sync (in-order DS)
        // ---- denominators: register-pe tree (DS pipe, overlaps gather) -----
        float sp0 = pe.x, sp1 = pe.y, sp2 = pe.z, sp3 = pe.w;
#pragma unroll
        for (int off = 1; off < 64; off <<= 1) {
            sp0 += __shfl_xor(sp0, off, 64);
            sp1 += __shfl_xor(sp1, off, 64);
            sp2 += __shfl_xor(sp2, off, 64);
            sp3 += __shfl_xor(sp3, off, 64);
        }
        // ---- gather loop: per round, half h processes edge 2r+h ------------
        float a0 = 0.f, a1 = 0.f, a2 = 0.f, a3 = 0.f;       // a[h*2+t]
        float a4 = 0.f, a5 = 0.f, a6 = 0.f, a7 = 0.f;
        const int nr = (n + 2) >> 1;                        // rounds (n+1 entries)
        const int*    cB = cSw + hlf * 32;                  // my half's col list
        const float4* pB = peSw + hlf * 32;
#define ACC2(D, P) { float x0 = hbits((unsigned short)((D) & 0xffff)); \
                     float x1 = hbits((unsigned short)((D) >> 16)); \
                     a0 = fmaf((P).x, x0, a0); a1 = fmaf((P).x, x1, a1); \
                     a2 = fmaf((P).y, x0, a2); a3 = fmaf((P).y, x1, a3); \
                     a4 = fmaf((P).z, x0, a4); a5 = fmaf((P).z, x1, a5); \
                     a6 = fmaf((P).w, x0, a6); a7 = fmaf((P).w, x1, a7); }
        int r = 0;
        for (; r + 8 <= nr; r += 8) {                       // 16 loads in flight
            const int4 cc0 = *(const int4*)(cB + r);
            const int4 cc1 = *(const int4*)(cB + r + 4);
            unsigned dA = *(const unsigned*)(xb + cc0.x);
            unsigned dB = *(const unsigned*)(xb + cc0.y);
            unsigned dC = *(const unsigned*)(xb + cc0.z);
            unsigned dD = *(const unsigned*)(xb + cc0.w);
            unsigned dE = *(const unsigned*)(xb + cc1.x);
            unsigned dF = *(const unsigned*)(xb + cc1.y);
            unsigned dG = *(const unsigned*)(xb + cc1.z);
            unsigned dH = *(const unsigned*)(xb + cc1.w);
            float4 pA = pB[r],     pBv = pB[r + 1];
            float4 pC = pB[r + 2], pD  = pB[r + 3];
            float4 pE = pB[r + 4], pF  = pB[r + 5];
            float4 pG = pB[r + 6], pH  = pB[r + 7];
            ACC2(dA, pA); ACC2(dB, pBv); ACC2(dC, pC); ACC2(dD, pD);
            ACC2(dE, pE); ACC2(dF, pF);  ACC2(dG, pG); ACC2(dH, pH);
        }
        for (; r + 4 <= nr; r += 4) {
            const int4 cc = *(const int4*)(cB + r);
            unsigned dA = *(const unsigned*)(xb + cc.x);
            unsigned dB = *(const unsigned*)(xb + cc.y);
            unsigned dC = *(const unsigned*)(xb + cc.z);
            unsigned dD = *(const unsigned*)(xb + cc.w);
            float4 pA = pB[r], pBv = pB[r + 1], pC = pB[r + 2], pD = pB[r + 3];
            ACC2(dA, pA); ACC2(dB, pBv); ACC2(dC, pC); ACC2(dD, pD);
        }
        for (; r < nr; ++r) {
            int c = cB[r];
            unsigned d = *(const unsigned*)(xb + c);
            float4 p = pB[r];
            ACC2(d, p);
        }
#undef ACC2
        // ---- fold the two 32-lane halves (same dims, disjoint edges) -------
        a0 += __shfl_xor(a0, 32, 64); a1 += __shfl_xor(a1, 32, 64);
        a2 += __shfl_xor(a2, 32, 64); a3 += __shfl_xor(a3, 32, 64);
        a4 += __shfl_xor(a4, 32, 64); a5 += __shfl_xor(a5, 32, 64);
        a6 += __shfl_xor(a6, 32, 64); a7 += __shfl_xor(a7, 32, 64);
        const float r0 = 1.f / sp0, r1 = 1.f / sp1;
        const float r2 = 1.f / sp2, r3 = 1.f / sp3;
        // ---- normalize + stage s row into LDS (identical f2h packing) ------
        if (lane < 32) {
            unsigned* sr = sS + (wav * 4 + nid) * 132;      // pitch 132 dwords
            sr[l5]      = (unsigned)f2h(a0 * r0) | ((unsigned)f2h(a1 * r0) << 16);
            sr[32 + l5] = (unsigned)f2h(a2 * r1) | ((unsigned)f2h(a3 * r1) << 16);
            sr[64 + l5] = (unsigned)f2h(a4 * r2) | ((unsigned)f2h(a5 * r2) << 16);
            sr[96 + l5] = (unsigned)f2h(a6 * r3) | ((unsigned)f2h(a7 * r3) << 16);
        }
        cval = cval_next;
    }
    __syncthreads();
    // ---- post phase: ALL 4 waves, wave = n-tile nt --------------------------
    {
        const int nt = wav;
        f32x4 acc = (f32x4){0.f, 0.f, 0.f, 0.f};
        const half8* bp = (const half8*)Bpost;
#pragma unroll
        for (int kt = 0; kt < 8; ++kt) {
            half8 af = *(const half8*)&sS[r15 * 132 + kt * 16 + quad * 4];
            acc = __builtin_amdgcn_mfma_f32_16x16x32_f16(
                af, bp[(kt * 4 + nt) * 64 + lane], acc, 0, 0, 0);
        }
        const float bi = cvt<T>(bias[nt * 16 + r15]);
        const float fw = cvt<T>(fc_w[nt * 16 + r15]);
#pragma unroll
        for (int rr = 0; rr < 4; ++rr) {
            float o = acc[rr] + bi;
            o = o > 0.f ? o : 0.f;              // relu
            float p = o * fw;
            p += __shfl_xor(p, 1, 64); p += __shfl_xor(p, 2, 64);
            p += __shfl_xor(p, 4, 64); p += __shfl_xor(p, 8, 64);
            if (r15 == 0) postS[(quad * 4 + rr) * 4 + nt] = p;
        }
    }
    __syncthreads();
    if (tid < 16) {
        float o = postS[tid * 4] + postS[tid * 4 + 1]
                + postS[tid * 4 + 2] + postS[tid * 4 + 3] + cvt<T>(fc_b[0]);
        out[blockIdx.x * 16 + tid] = o;
    }
}

__global__ __launch_bounds__(256) void k_aggregate(
        const unsigned short* __restrict__ col_pad,
        const float* __restrict__ a_src,
        const float* __restrict__ a_dst,
        const unsigned short* __restrict__ x16,
        const unsigned short* __restrict__ Bpost,
        const void* __restrict__ bias,
        const void* __restrict__ fc_w,
        const void* __restrict__ fc_b,
        const int* __restrict__ flags,
        float* __restrict__ out) {
    __shared__ __align__(16) int cS[4 * 64];    // parity-interleaved col lists
    __shared__ float4 peS[4 * 64];
    __shared__ __align__(16) unsigned sS[16 * 132];  // staged s rows (f16 pairs)
    __shared__ float postS[16 * 4];
    if (flags[1])
        agg_body<float>(col_pad, a_src, a_dst, x16, Bpost, (const float*)bias,
                        (const float*)fc_w, (const float*)fc_b, out,
                        cS, peS, sS, postS);
    else
        agg_body<__hip_bfloat16>(col_pad, a_src, a_dst, x16, Bpost,
                                 (const __hip_bfloat16*)bias,
                                 (const __hip_bfloat16*)fc_w,
                                 (const __hip_bfloat16*)fc_b, out,
                                 cS, peS, sS, postS);
}

extern "C" void kernel_launch(void* const* d_in, const int* in_sizes, int n_in,
                              void* d_out, int out_size, void* d_ws, size_t ws_size,
                              hipStream_t stream) {
    const void* x       = d_in[0];
    const int*  ei      = (const int*)d_in[1];
    const void* W       = d_in[2];
    const void* att_src = d_in[3];
    const void* att_dst = d_in[4];
    const void* bias    = d_in[5];
    const void* fc_w    = d_in[6];
    const void* fc_b    = d_in[7];
    float* out = (float*)d_out;

    char* wsb = (char*)d_ws;                                      // ~19.3 MB total
    unsigned short* x16   = (unsigned short*)wsb;                 // 6.4 MB (f16 x)
    unsigned*       queue = (unsigned*)(wsb + 6400000);           // 4.8 MB (8 subQ)
    unsigned short* col_pad = (unsigned short*)(wsb + 11204608);  // 6.4 MB (128B-align)
    float* a_src = (float*)(wsb + 17604608);                      // 800 KB
    float* a_dst = (float*)(wsb + 18404608);                      // 800 KB
    unsigned short* Batt  = (unsigned short*)(wsb + 19204608);    // 2 KB
    unsigned short* Bpost = (unsigned short*)(wsb + 19206656);    // 32 KB
    int* flags = (int*)(wsb + 19239424);                          // 8 B
    int* qcnt  = (int*)(wsb + 19239432);                          // 12.5 KB (8xNREG)

    k_init<<<6, 256, 0, stream>>>((const unsigned*)x, ei, W, att_src,
                                  att_dst, qcnt, flags, Batt, Bpost);
    k_mid<<<NT, 256, 0, stream>>>(x, Batt, ei, flags, qcnt, queue,
                                  x16, a_src, a_dst);
    k_scat<<<NREG, 256, 0, stream>>>(queue, qcnt, col_pad);
    k_aggregate<<<NAGG, 256, 0, stream>>>(col_pad, a_src, a_dst, x16, Bpost,
                                          bias, fc_w, fc_b, flags, out);
}

// Round 14
// 156.152 us; speedup vs baseline: 1.0833x; 1.0833x over previous
//
#include <hip/hip_runtime.h>
#include <hip/hip_bf16.h>

#define N_NODES 50000
#define N_EDGES 800000
#define HEADS   4
#define NEG_SLOPE 0.2f
#define CAP     64                    // bucket row: 63 edge slots + count in slot 63
#define NT      ((N_NODES + 63) / 64)       // 782 row blocks
#define EPB     2048                  // edges per edge-block
#define NREG    391                   // regions of 128 nodes (dst>>7)
#define NREP    8                     // qcnt replicas (kills same-addr atomic chain)
#define QSUB    384                   // sub-queue cap: mean 256 + 8 sigma
#define NAGG    (N_NODES / 16)        // 3125 agg blocks (EXACT: 16*3125 = 50000)
#define INV_LN2 1.44269504088896340736f

typedef __attribute__((ext_vector_type(8))) _Float16 half8;  // 8 f16 (4 VGPRs)
typedef __attribute__((ext_vector_type(4))) float f32x4;     // MFMA acc
typedef __attribute__((ext_vector_type(8))) unsigned short u16x8; // 16B of f16 bits

template <typename T> __device__ __forceinline__ float cvt(T v);
template <> __device__ __forceinline__ float cvt<float>(float v) { return v; }
template <> __device__ __forceinline__ float cvt<__hip_bfloat16>(__hip_bfloat16 v) {
    return __bfloat162float(v);
}
__device__ __forceinline__ unsigned short f2h(float f) {     // f32 -> f16 bits (RNE)
    _Float16 h = (_Float16)f;
    return __builtin_bit_cast(unsigned short, h);
}
__device__ __forceinline__ float hbits(unsigned short u) {   // f16 bits -> f32
    return (float)__builtin_bit_cast(_Float16, u);           // folds into v_fma_mix
}
__device__ __forceinline__ int probe_fp32(const unsigned* xw) {
    int sane = 0;
    for (int j = 0; j < 64; ++j) {
        unsigned e = (xw[j] >> 7) & 0xFF;    // exponent of low half viewed as bf16
        sane += (e >= 90 && e <= 141);
    }
    return sane < 32;                        // junk low halves => fp32 buffer
}
__device__ __forceinline__ float loadW(int isf32, const void* W, int idx) {
    return isf32 ? ((const float*)W)[idx]
                 : cvt<__hip_bfloat16>(((const __hip_bfloat16*)W)[idx]);
}

// load 8 contiguous elems as f16, vectorized (b128 loads)
template <typename T>
__device__ __forceinline__ void load8_f16(const T* p, _Float16* dst);
template <>
__device__ __forceinline__ void load8_f16<float>(const float* p, _Float16* dst) {
    float4 a = *(const float4*)p;            // 32B-aligned (offsets are 8-float mult.)
    float4 b = *(const float4*)(p + 4);
    dst[0] = (_Float16)a.x; dst[1] = (_Float16)a.y;
    dst[2] = (_Float16)a.z; dst[3] = (_Float16)a.w;
    dst[4] = (_Float16)b.x; dst[5] = (_Float16)b.y;
    dst[6] = (_Float16)b.z; dst[7] = (_Float16)b.w;
}
template <>
__device__ __forceinline__ void load8_f16<__hip_bfloat16>(const __hip_bfloat16* p,
                                                          _Float16* dst) {
    uint4 a = *(const uint4*)p;              // 8 bf16 = 16B
    const unsigned short* u = (const unsigned short*)&a;
#pragma unroll
    for (int j = 0; j < 8; ++j)
        dst[j] = (_Float16)__uint_as_float(((unsigned)u[j]) << 16);
}

// ------------- fused init: probes + zero qcnt + pack Batt + Bpost -----------
// flags[0]: edge_index is int64. flags[1]: float inputs are fp32.
// Block 0: flags + zero qcnt (8 replicas). Block 1: att-fold Batt = (W @ a)/ln2
// in MFMA-B layout. Blocks 2..5: Bpost = Wstack[256,64]/4 in MFMA-B layout,
// Wstack[h*64+k, c] = W[k, h*64+c] (mean folded). B layout (HW-verified):
// within one K=32 MFMA, value(l,j)=B[k=(l>>4)*8+j][n=l&15].
__global__ __launch_bounds__(256) void k_init(const unsigned* __restrict__ xw,
                                              const int* __restrict__ ei,
                                              const void* __restrict__ W,
                                              const void* __restrict__ att_src,
                                              const void* __restrict__ att_dst,
                                              int* __restrict__ qcnt,
                                              int* __restrict__ flags,
                                              unsigned short* __restrict__ Batt,
                                              unsigned short* __restrict__ Bpost) {
    __shared__ float waS[256], waD[256];
    __shared__ int f32sh;
    if (blockIdx.x == 0) {
        for (int t = threadIdx.x; t < NREP * NREG; t += 256) qcnt[t] = 0;
        if (threadIdx.x == 0) {
            int all0 = 1;
            for (int j = 1; j < 64; j += 2) all0 &= (ei[j] == 0);
            flags[0] = all0;
            flags[1] = probe_fp32(xw);
        }
        return;
    }
    const int pb = blockIdx.x - 1;           // 0 = att fold, 1..4 = Bpost
    if (threadIdx.x == 0) f32sh = probe_fp32(xw);   // local probe (race-free)
    __syncthreads();
    const int isf32 = f32sh;
    if (pb == 0) {
        int t = threadIdx.x, k = t >> 2, h = t & 3;
        float s = 0.f, d = 0.f;
        for (int c = 0; c < 64; ++c) {
            float w = loadW(isf32, W, k * 256 + h * 64 + c);
            float as = isf32 ? ((const float*)att_src)[h * 64 + c]
                             : cvt<__hip_bfloat16>(((const __hip_bfloat16*)att_src)[h * 64 + c]);
            float ad = isf32 ? ((const float*)att_dst)[h * 64 + c]
                             : cvt<__hip_bfloat16>(((const __hip_bfloat16*)att_dst)[h * 64 + c]);
            s = fmaf(w, as, s);
            d = fmaf(w, ad, d);
        }
        waS[t] = s * INV_LN2;
        waD[t] = d * INV_LN2;
        __syncthreads();
        if (threadIdx.x < 128) {
            int r = threadIdx.x;             // r = q*64 + l, q = K-half
            int q = (r >> 6) & 1, l = r & 63, n = l & 15;
            int kbase = q * 32 + ((l >> 4) & 3) * 8;
#pragma unroll
            for (int j = 0; j < 8; ++j) {
                int kk = kbase + j;
                float v = (n < 4) ? waS[kk * 4 + n]
                        : (n < 8) ? waD[kk * 4 + (n - 4)] : 0.f;
                Batt[r * 8 + j] = f2h(v);
            }
        }
    } else {
        // Bpost: tile t = kt*4+nt (t = 0..31); this block packs 8 tiles.
        const int sub = threadIdx.x >> 5, s = threadIdx.x & 31;
        const int t = (pb - 1) * 8 + sub;
        const int kt = t >> 2, nt = t & 3;
#pragma unroll
        for (int e = 0; e < 16; ++e) {
            int idx = s * 16 + e;            // 0..511 within tile
            int l = idx >> 3, j = idx & 7;
            int rs = kt * 32 + ((l >> 4) & 3) * 8 + j;   // row of Wstack (0..255)
            int h = rs >> 6, k_in = rs & 63;
            int c = nt * 16 + (l & 15);
            Bpost[t * 512 + l * 8 + j] =
                f2h(loadW(isf32, W, k_in * 256 + h * 64 + c) * 0.25f);
        }
    }
}

// ---------------- logits + x->f16 from MFMA afrags (all k_mid blocks) --------
// Block = 64 rows, 4 waves; wave w: rows 16w..16w+15; single n-tile (Batt).
// C layout (HW-verified): col=lane&15, row=quad*4+reg. Cols 0..3 = a_src heads,
// 4..7 = a_dst heads (1/ln2-scaled) -> direct fp32 global writes.
// x16 is stored FROM the already-converted afrag registers.
template <typename T>
__device__ __forceinline__ void row_body(const T* __restrict__ x,
                                         const unsigned short* __restrict__ Batt,
                                         unsigned short* __restrict__ x16,
                                         float* __restrict__ a_src,
                                         float* __restrict__ a_dst) {
    const int tid = threadIdx.x;
    const int wav = tid >> 6, lane = tid & 63;
    const int quad = lane >> 4, r15 = lane & 15;
    const int m0 = blockIdx.x * 64;
    const int grow_a = m0 + wav * 16 + r15;     // this lane's A row (m = lane&15)
    int gr = grow_a;
    if (gr >= N_NODES) gr = N_NODES - 1;        // clamp; stores guarded
    half8 afrag[2];
#pragma unroll
    for (int q = 0; q < 2; ++q) {
        _Float16 tmp[8];
        load8_f16<T>(x + (size_t)gr * 64 + q * 32 + quad * 8, tmp);
#pragma unroll
        for (int j = 0; j < 8; ++j) afrag[q][j] = tmp[j];
    }
    // ---- f16 copy of x straight from registers (16B per store, full lines) -
    if (grow_a < N_NODES) {
#pragma unroll
        for (int q = 0; q < 2; ++q)
            *(half8*)(x16 + (size_t)grow_a * 64 + q * 32 + quad * 8) = afrag[q];
    }
    f32x4 acc = (f32x4){0.f, 0.f, 0.f, 0.f};
    const half8* bp = (const half8*)Batt;
    acc = __builtin_amdgcn_mfma_f32_16x16x32_f16(afrag[0], bp[lane], acc, 0, 0, 0);
    acc = __builtin_amdgcn_mfma_f32_16x16x32_f16(afrag[1], bp[64 + lane], acc, 0, 0, 0);
    if (r15 < 8) {
#pragma unroll
        for (int r = 0; r < 4; ++r) {
            int grow = m0 + wav * 16 + quad * 4 + r;
            if (grow < N_NODES) {
                if (r15 < 4) a_src[grow * HEADS + r15]       = acc[r];
                else         a_dst[grow * HEADS + (r15 - 4)] = acc[r];
            }
        }
    }
}

// ---------------- fused mid: rows + REGION-BUCKETED edge append -------------
// Even blocks bucket EPB=2048 edges into 391 region queues (region = dst>>7)
// as packed 4B records. Edge loads PAIRED (int4/int2) for full-line use.
// qcnt is REPLICATED 8x (replica = eb&7) — kills the same-address device-scope
// atomic RMW chain (391 adds/address -> ~49). Queue = [region][replica][QSUB].
__global__ __launch_bounds__(256) void k_mid(const void* __restrict__ x,
                                             const unsigned short* __restrict__ Batt,
                                             const int* __restrict__ ei,
                                             const int* __restrict__ flags,
                                             int* __restrict__ qcnt,
                                             unsigned* __restrict__ queue,
                                             unsigned short* __restrict__ x16,
                                             float* __restrict__ a_src,
                                             float* __restrict__ a_dst) {
    __shared__ int hist[NREG];
    __shared__ int qbaseS[NREG];
    const int tid = threadIdx.x;
    const bool edge_blk = ((blockIdx.x & 1) == 0);   // interleaved for CU balance
    const int eb = blockIdx.x >> 1;                  // 0..390
    const int rep = eb & (NREP - 1);                 // my qcnt replica
    unsigned rec[8]; int reg[8], lpos[8];
    int histv0 = 0, histv1 = 0, mybase0 = 0, mybase1 = 0;
    if (edge_blk) {
        for (int t = tid; t < NREG; t += 256) hist[t] = 0;
        __syncthreads();
        const int f64 = flags[0];
        const int pbase = eb * 1024 + tid;           // pair index (2 edges/pair)
#pragma unroll
        for (int k = 0; k < 4; ++k) {
            int pid = pbase + k * 256;
            int e = 2 * pid;
            if (e < N_EDGES) {                       // N_EDGES even => e+1 valid
                int s0, d0, s1, d1;
                if (f64) {                           // 16B = 2 int64 edges
                    int4 sv = *(const int4*)(ei + 2 * e);
                    int4 dv = *(const int4*)(ei + 2 * N_EDGES + 2 * e);
                    s0 = sv.x; s1 = sv.z; d0 = dv.x; d1 = dv.z;
                } else {                             // 8B = 2 int32 edges
                    int2 sv = *(const int2*)(ei + e);
                    int2 dv = *(const int2*)(ei + N_EDGES + e);
                    s0 = sv.x; s1 = sv.y; d0 = dv.x; d1 = dv.y;
                }
                reg[2 * k]     = d0 >> 7;
                rec[2 * k]     = (unsigned)s0 | ((unsigned)d0 << 16);
                reg[2 * k + 1] = d1 >> 7;
                rec[2 * k + 1] = (unsigned)s1 | ((unsigned)d1 << 16);
            } else { reg[2 * k] = -1; reg[2 * k + 1] = -1; }
        }
#pragma unroll
        for (int k = 0; k < 8; ++k)
            if (reg[k] >= 0) lpos[k] = atomicAdd(&hist[reg[k]], 1);
        __syncthreads();
        {   // qcnt atomics issued BEFORE row_body (round trip hides under it)
            int t0 = tid, t1 = tid + 256;
            histv0 = hist[t0];
            if (histv0) mybase0 = atomicAdd(qcnt + rep * NREG + t0, histv0);
            if (t1 < NREG) {
                histv1 = hist[t1];
                if (histv1) mybase1 = atomicAdd(qcnt + rep * NREG + t1, histv1);
            }
        }
    }
    // ---- rows for ALL blocks ----
    if (flags[1]) row_body<float>((const float*)x, Batt, x16, a_src, a_dst);
    else          row_body<__hip_bfloat16>((const __hip_bfloat16*)x, Batt,
                                           x16, a_src, a_dst);
    if (edge_blk) {
        qbaseS[tid] = mybase0;
        if (tid + 256 < NREG) qbaseS[tid + 256] = mybase1;
        __syncthreads();
#pragma unroll
        for (int k = 0; k < 8; ++k)
            if (reg[k] >= 0) {
                int o = qbaseS[reg[k]] + lpos[k];
                if (o < QSUB)
                    queue[((size_t)reg[k] * NREP + rep) * QSUB + o] = rec[k];
            }
    }
}

// ---------------- scat: per-region 8 sub-queues -> col_pad (L2-local) -------
// One block per 128-node region (16 KB col_pad window, single-XCD L2).
// Positions via LDS atomics. Per-node count stored IN col_pad slot 63
// (self-loop occupies lane n <= 63, so slot 63 is never an edge slot).
__global__ __launch_bounds__(256) void k_scat(const unsigned* __restrict__ queue,
                                              const int* __restrict__ qcnt,
                                              unsigned short* __restrict__ col_pad) {
    __shared__ int cl[128];
    __shared__ int mr[NREP];
    const int b = blockIdx.x, tid = threadIdx.x;
    const int base = b << 7;
    if (tid < 128) cl[tid] = 0;
    if (tid < NREP) {
        int m = qcnt[tid * NREG + b];
        mr[tid] = m > QSUB ? QSUB : m;
    }
    __syncthreads();
#pragma unroll
    for (int rep = 0; rep < NREP; ++rep) {
        int m = mr[rep];
        const unsigned* q = queue + ((size_t)b * NREP + rep) * QSUB;
        for (int i = tid; i < m; i += 256) {
            unsigned rec = q[i];
            int d = rec >> 16, s = rec & 0xffff;
            int p = atomicAdd(&cl[d - base], 1);
            if (p < CAP - 1) col_pad[(size_t)d * CAP + p] = (unsigned short)s;
        }
    }
    __syncthreads();
    if (tid < 128) {
        int j = base + tid;
        if (j < N_NODES) {
            int c = cl[tid]; c = c > CAP - 1 ? CAP - 1 : c;
            col_pad[(size_t)j * CAP + (CAP - 1)] = (unsigned short)c;
        }
    }
}

// -------- fused aggregate+post (R10/R12 structure — best known) -------------
// 16 nodes/block, 256 thr / 4 waves, 4 serial nodes/wave; 2 edges/round with
// parity-interleaved col/pe lists; unroll-8; count from col_pad slot 63;
// IN-LOOP denominators (R13 lesson: hidden VALU work beats serial shfl chain);
// phase 2: 16 staged rows = one MFMA M-tile, all 4 waves (wave = n-tile).
template <typename T>
__device__ __forceinline__ void agg_body(const unsigned short* __restrict__ col_pad,
                                         const float* __restrict__ a_src,
                                         const float* __restrict__ a_dst,
                                         const unsigned short* __restrict__ x16,
                                         const unsigned short* __restrict__ Bpost,
                                         const T* __restrict__ bias,
                                         const T* __restrict__ fc_w,
                                         const T* __restrict__ fc_b,
                                         float* __restrict__ out,
                                         int* __restrict__ cS,
                                         float4* __restrict__ peS,
                                         unsigned* __restrict__ sS,
                                         float* __restrict__ postS) {
    const int tid = threadIdx.x;
    const int wav = tid >> 6, lane = tid & 63;
    const int hlf = lane >> 5, l5 = lane & 31;
    const int quad = lane >> 4, r15 = lane & 15;
    const int nbase = blockIdx.x * 16 + wav * 4;            // 4 serial nodes/wave
    int* cSw = cS + wav * 64;
    float4* peSw = peS + wav * 64;
    const int slot = (lane & 1) * 32 + (lane >> 1);         // parity interleave
    const char* xb = (const char*)x16 + l5 * 4;             // my dim-pair slice
    int cval = (int)col_pad[(size_t)nbase * CAP + lane];    // node 0 row
#pragma unroll
    for (int nid = 0; nid < 4; ++nid) {
        const int wid = nbase + nid;
        int cval_next = 0;
        if (nid < 3)                                        // prefetch next row:
            cval_next = (int)col_pad[(size_t)(wid + 1) * CAP + lane];
        const int n = __shfl(cval, 63, 64);                 // count from slot 63
        const float4 ad = ((const float4*)a_dst)[wid];      // uniform
        const int mycol = (lane < n) ? cval : wid;          // lane n = self loop
        const float4 as = ((const float4*)a_src)[mycol];
        float e0 = as.x + ad.x, e1 = as.y + ad.y;
        float e2 = as.z + ad.z, e3 = as.w + ad.w;
        e0 = e0 > 0.f ? e0 : NEG_SLOPE * e0;  e1 = e1 > 0.f ? e1 : NEG_SLOPE * e1;
        e2 = e2 > 0.f ? e2 : NEG_SLOPE * e2;  e3 = e3 > 0.f ? e3 : NEG_SLOPE * e3;
        float4 pe = make_float4(exp2f(e0), exp2f(e1), exp2f(e2), exp2f(e3));
        if (lane > n) pe = make_float4(0.f, 0.f, 0.f, 0.f); // pad lanes
        cSw[slot] = mycol << 7;                             // x16 row BYTE offset
        peSw[slot] = pe;                                    // wave-sync (in-order DS)
        // ---- gather loop: per round, half h processes edge 2r+h ------------
        float a0 = 0.f, a1 = 0.f, a2 = 0.f, a3 = 0.f;       // a[h*2+t]
        float a4 = 0.f, a5 = 0.f, a6 = 0.f, a7 = 0.f;
        float sp0 = 0.f, sp1 = 0.f, sp2 = 0.f, sp3 = 0.f;   // my half's denom
        const int nr = (n + 2) >> 1;                        // rounds (n+1 entries)
        const int*    cB = cSw + hlf * 32;                  // my half's col list
        const float4* pB = peSw + hlf * 32;
#define ACC2(D, P) { float x0 = hbits((unsigned short)((D) & 0xffff)); \
                     float x1 = hbits((unsigned short)((D) >> 16)); \
                     a0 = fmaf((P).x, x0, a0); a1 = fmaf((P).x, x1, a1); \
                     a2 = fmaf((P).y, x0, a2); a3 = fmaf((P).y, x1, a3); \
                     a4 = fmaf((P).z, x0, a4); a5 = fmaf((P).z, x1, a5); \
                     a6 = fmaf((P).w, x0, a6); a7 = fmaf((P).w, x1, a7); \
                     sp0 += (P).x; sp1 += (P).y; sp2 += (P).z; sp3 += (P).w; }
        int r = 0;
        for (; r + 8 <= nr; r += 8) {                       // 16 loads in flight
            const int4 cc0 = *(const int4*)(cB + r);
            const int4 cc1 = *(const int4*)(cB + r + 4);
            unsigned dA = *(const unsigned*)(xb + cc0.x);
            unsigned dB = *(const unsigned*)(xb + cc0.y);
            unsigned dC = *(const unsigned*)(xb + cc0.z);
            unsigned dD = *(const unsigned*)(xb + cc0.w);
            unsigned dE = *(const unsigned*)(xb + cc1.x);
            unsigned dF = *(const unsigned*)(xb + cc1.y);
            unsigned dG = *(const unsigned*)(xb + cc1.z);
            unsigned dH = *(const unsigned*)(xb + cc1.w);
            float4 pA = pB[r],     pBv = pB[r + 1];
            float4 pC = pB[r + 2], pD  = pB[r + 3];
            float4 pE = pB[r + 4], pF  = pB[r + 5];
            float4 pG = pB[r + 6], pH  = pB[r + 7];
            ACC2(dA, pA); ACC2(dB, pBv); ACC2(dC, pC); ACC2(dD, pD);
            ACC2(dE, pE); ACC2(dF, pF);  ACC2(dG, pG); ACC2(dH, pH);
        }
        for (; r + 4 <= nr; r += 4) {
            const int4 cc = *(const int4*)(cB + r);
            unsigned dA = *(const unsigned*)(xb + cc.x);
            unsigned dB = *(const unsigned*)(xb + cc.y);
            unsigned dC = *(const unsigned*)(xb + cc.z);
            unsigned dD = *(const unsigned*)(xb + cc.w);
            float4 pA = pB[r], pBv = pB[r + 1], pC = pB[r + 2], pD = pB[r + 3];
            ACC2(dA, pA); ACC2(dB, pBv); ACC2(dC, pC); ACC2(dD, pD);
        }
        for (; r < nr; ++r) {
            int c = cB[r];
            unsigned d = *(const unsigned*)(xb + c);
            float4 p = pB[r];
            ACC2(d, p);
        }
#undef ACC2
        // ---- fold the two 32-lane halves (same dims, disjoint edges) -------
        a0 += __shfl_xor(a0, 32, 64); a1 += __shfl_xor(a1, 32, 64);
        a2 += __shfl_xor(a2, 32, 64); a3 += __shfl_xor(a3, 32, 64);
        a4 += __shfl_xor(a4, 32, 64); a5 += __shfl_xor(a5, 32, 64);
        a6 += __shfl_xor(a6, 32, 64); a7 += __shfl_xor(a7, 32, 64);
        sp0 += __shfl_xor(sp0, 32, 64); sp1 += __shfl_xor(sp1, 32, 64);
        sp2 += __shfl_xor(sp2, 32, 64); sp3 += __shfl_xor(sp3, 32, 64);
        const float r0 = 1.f / sp0, r1 = 1.f / sp1;
        const float r2 = 1.f / sp2, r3 = 1.f / sp3;
        // ---- normalize + stage s row into LDS (identical f2h packing) ------
        if (lane < 32) {
            unsigned* sr = sS + (wav * 4 + nid) * 132;      // pitch 132 dwords
            sr[l5]      = (unsigned)f2h(a0 * r0) | ((unsigned)f2h(a1 * r0) << 16);
            sr[32 + l5] = (unsigned)f2h(a2 * r1) | ((unsigned)f2h(a3 * r1) << 16);
            sr[64 + l5] = (unsigned)f2h(a4 * r2) | ((unsigned)f2h(a5 * r2) << 16);
            sr[96 + l5] = (unsigned)f2h(a6 * r3) | ((unsigned)f2h(a7 * r3) << 16);
        }
        cval = cval_next;
    }
    __syncthreads();
    // ---- post phase: ALL 4 waves, wave = n-tile nt --------------------------
    {
        const int nt = wav;
        f32x4 acc = (f32x4){0.f, 0.f, 0.f, 0.f};
        const half8* bp = (const half8*)Bpost;
#pragma unroll
        for (int kt = 0; kt < 8; ++kt) {
            half8 af = *(const half8*)&sS[r15 * 132 + kt * 16 + quad * 4];
            acc = __builtin_amdgcn_mfma_f32_16x16x32_f16(
                af, bp[(kt * 4 + nt) * 64 + lane], acc, 0, 0, 0);
        }
        const float bi = cvt<T>(bias[nt * 16 + r15]);
        const float fw = cvt<T>(fc_w[nt * 16 + r15]);
#pragma unroll
        for (int rr = 0; rr < 4; ++rr) {
            float o = acc[rr] + bi;
            o = o > 0.f ? o : 0.f;              // relu
            float p = o * fw;
            p += __shfl_xor(p, 1, 64); p += __shfl_xor(p, 2, 64);
            p += __shfl_xor(p, 4, 64); p += __shfl_xor(p, 8, 64);
            if (r15 == 0) postS[(quad * 4 + rr) * 4 + nt] = p;
        }
    }
    __syncthreads();
    if (tid < 16) {
        float o = postS[tid * 4] + postS[tid * 4 + 1]
                + postS[tid * 4 + 2] + postS[tid * 4 + 3] + cvt<T>(fc_b[0]);
        out[blockIdx.x * 16 + tid] = o;
    }
}

__global__ __launch_bounds__(256) void k_aggregate(
        const unsigned short* __restrict__ col_pad,
        const float* __restrict__ a_src,
        const float* __restrict__ a_dst,
        const unsigned short* __restrict__ x16,
        const unsigned short* __restrict__ Bpost,
        const void* __restrict__ bias,
        const void* __restrict__ fc_w,
        const void* __restrict__ fc_b,
        const int* __restrict__ flags,
        float* __restrict__ out) {
    __shared__ __align__(16) int cS[4 * 64];    // parity-interleaved col lists
    __shared__ float4 peS[4 * 64];
    __shared__ __align__(16) unsigned sS[16 * 132];  // staged s rows (f16 pairs)
    __shared__ float postS[16 * 4];
    if (flags[1])
        agg_body<float>(col_pad, a_src, a_dst, x16, Bpost, (const float*)bias,
                        (const float*)fc_w, (const float*)fc_b, out,
                        cS, peS, sS, postS);
    else
        agg_body<__hip_bfloat16>(col_pad, a_src, a_dst, x16, Bpost,
                                 (const __hip_bfloat16*)bias,
                                 (const __hip_bfloat16*)fc_w,
                                 (const __hip_bfloat16*)fc_b, out,
                                 cS, peS, sS, postS);
}

extern "C" void kernel_launch(void* const* d_in, const int* in_sizes, int n_in,
                              void* d_out, int out_size, void* d_ws, size_t ws_size,
                              hipStream_t stream) {
    const void* x       = d_in[0];
    const int*  ei      = (const int*)d_in[1];
    const void* W       = d_in[2];
    const void* att_src = d_in[3];
    const void* att_dst = d_in[4];
    const void* bias    = d_in[5];
    const void* fc_w    = d_in[6];
    const void* fc_b    = d_in[7];
    float* out = (float*)d_out;

    char* wsb = (char*)d_ws;                                      // ~19.3 MB total
    unsigned short* x16   = (unsigned short*)wsb;                 // 6.4 MB (f16 x)
    unsigned*       queue = (unsigned*)(wsb + 6400000);           // 4.8 MB (8 subQ)
    unsigned short* col_pad = (unsigned short*)(wsb + 11204608);  // 6.4 MB (128B-align)
    float* a_src = (float*)(wsb + 17604608);                      // 800 KB
    float* a_dst = (float*)(wsb + 18404608);                      // 800 KB
    unsigned short* Batt  = (unsigned short*)(wsb + 19204608);    // 2 KB
    unsigned short* Bpost = (unsigned short*)(wsb + 19206656);    // 32 KB
    int* flags = (int*)(wsb + 19239424);                          // 8 B
    int* qcnt  = (int*)(wsb + 19239432);                          // 12.5 KB (8xNREG)

    k_init<<<6, 256, 0, stream>>>((const unsigned*)x, ei, W, att_src,
                                  att_dst, qcnt, flags, Batt, Bpost);
    k_mid<<<NT, 256, 0, stream>>>(x, Batt, ei, flags, qcnt, queue,
                                  x16, a_src, a_dst);
    k_scat<<<NREG, 256, 0, stream>>>(queue, qcnt, col_pad);
    k_aggregate<<<NAGG, 256, 0, stream>>>(col_pad, a_src, a_dst, x16, Bpost,
                                          bias, fc_w, fc_b, flags, out);
}